// Round 5
// baseline (1957.338 us; speedup 1.0000x reference)
//
#include <hip/hip_runtime.h>
#include <hip/hip_bf16.h>
#include <cstdint>
#include <cstddef>

// GCN: h1 = relu(GCNConv(x;W1,b1)); h2 = relu(GCNConv(h1;W2,b2));
// out = mean(h2,axis=0) @ Wf + bf
// Key factorization: agg[i] = dinv[i] * ( sum_{e:dst=i} hs[src_e] + hs[i] ),
// where hs = (X@W) * dinv[:,None].  CSR gather, no feature atomics.

#define HID 128

// ---- degree count ----
__global__ void k_deg(const int* __restrict__ dst, int* __restrict__ deg, int E) {
    int e = blockIdx.x * 256 + threadIdx.x;
    if (e < E) atomicAdd(&deg[dst[e]], 1);
}

// ---- single-block exclusive scan (N=100k) ----
__global__ void k_scan(const int* __restrict__ deg, int* __restrict__ off,
                       int* __restrict__ cursor, int n) {
    __shared__ int sb[1024];
    int t = threadIdx.x;
    int chunk = (n + 1023) >> 10;
    int lo = t * chunk;
    int hi = lo + chunk; if (hi > n) hi = n;
    int s = 0;
    for (int i = lo; i < hi; ++i) s += deg[i];
    sb[t] = s;
    __syncthreads();
    // Hillis-Steele inclusive scan
    for (int o = 1; o < 1024; o <<= 1) {
        int v = (t >= o) ? sb[t - o] : 0;
        __syncthreads();
        sb[t] += v;
        __syncthreads();
    }
    int base = sb[t] - s;   // exclusive prefix
    int run = base;
    for (int i = lo; i < hi; ++i) {
        off[i] = run; cursor[i] = run;
        run += deg[i];
    }
    if (t == 1023) off[n] = sb[1023];
}

__global__ void k_dinv(const int* __restrict__ deg, float* __restrict__ dinv, int n) {
    int i = blockIdx.x * 256 + threadIdx.x;
    if (i < n) dinv[i] = rsqrtf((float)(deg[i] + 1));
}

// ---- CSR fill ----
__global__ void k_fill(const int* __restrict__ src, const int* __restrict__ dst,
                       int* __restrict__ cursor, int* __restrict__ csr, int E) {
    int e = blockIdx.x * 256 + threadIdx.x;
    if (e < E) {
        int d = dst[e];
        int p = atomicAdd(&cursor[d], 1);
        csr[p] = src[e];
    }
}

// ---- conv1 pre-GEMM: hs = (x @ W1) * dinv  (K=3) ----
__global__ void k_gemm1(const float* __restrict__ x, const float* __restrict__ W1,
                        const float* __restrict__ dinv, float* __restrict__ hs, int n) {
    int tc = threadIdx.x & 31;   // 4-col group
    int tn = threadIdx.x >> 5;   // node within block (0..7)
    int i = blockIdx.x * 8 + tn;
    if (i >= n) return;
    float x0 = x[i * 3 + 0], x1 = x[i * 3 + 1], x2 = x[i * 3 + 2];
    float4 w0 = *(const float4*)&W1[0 * HID + tc * 4];
    float4 w1 = *(const float4*)&W1[1 * HID + tc * 4];
    float4 w2 = *(const float4*)&W1[2 * HID + tc * 4];
    float di = dinv[i];
    float4 r;
    r.x = (x0 * w0.x + x1 * w1.x + x2 * w2.x) * di;
    r.y = (x0 * w0.y + x1 * w1.y + x2 * w2.y) * di;
    r.z = (x0 * w0.z + x1 * w1.z + x2 * w2.z) * di;
    r.w = (x0 * w0.w + x1 * w1.w + x2 * w2.w) * di;
    *(float4*)&hs[(size_t)i * HID + tc * 4] = r;
}

// ---- tiled f32 GEMM: hs2 = (h1 @ W2) * dinv ; 64 rows x 128 cols per block ----
__global__ __launch_bounds__(256) void k_gemm2(const float* __restrict__ h,
                                               const float* __restrict__ W,
                                               const float* __restrict__ dinv,
                                               float* __restrict__ hs, int n) {
    __shared__ float hl[64][16];
    __shared__ float wl[16][128];
    int tid = threadIdx.x;
    int r0 = blockIdx.x * 64;
    int tr = tid >> 5;        // 0..7 (8 rows each)
    int tc = tid & 31;        // 4-col group
    float4 acc[8];
    #pragma unroll
    for (int r = 0; r < 8; ++r) acc[r] = make_float4(0.f, 0.f, 0.f, 0.f);

    for (int k0 = 0; k0 < HID; k0 += 16) {
        int lr = tid >> 2, lk = (tid & 3) * 4;
        float4 hv = make_float4(0.f, 0.f, 0.f, 0.f);
        if (r0 + lr < n) hv = *(const float4*)&h[(size_t)(r0 + lr) * HID + k0 + lk];
        *(float4*)&hl[lr][lk] = hv;
        #pragma unroll
        for (int q = 0; q < 2; ++q) {
            int idx = tid + q * 256;
            int kr = idx >> 5, c4 = (idx & 31) * 4;
            *(float4*)&wl[kr][c4] = *(const float4*)&W[(size_t)(k0 + kr) * HID + c4];
        }
        __syncthreads();
        #pragma unroll
        for (int kk = 0; kk < 16; ++kk) {
            float4 w = *(const float4*)&wl[kk][tc * 4];
            #pragma unroll
            for (int r = 0; r < 8; ++r) {
                float hv2 = hl[tr * 8 + r][kk];
                acc[r].x += hv2 * w.x; acc[r].y += hv2 * w.y;
                acc[r].z += hv2 * w.z; acc[r].w += hv2 * w.w;
            }
        }
        __syncthreads();
    }
    #pragma unroll
    for (int r = 0; r < 8; ++r) {
        int row = r0 + tr * 8 + r;
        if (row < n) {
            float di = dinv[row];
            float4 v = acc[r];
            v.x *= di; v.y *= di; v.z *= di; v.w *= di;
            *(float4*)&hs[(size_t)row * HID + tc * 4] = v;
        }
    }
}

// ---- aggregation (gather): one wave per node; optionally fuse pool+Wf dot ----
template <bool POOL>
__global__ void k_agg(const float* __restrict__ hs, const float* __restrict__ dinv,
                      const int* __restrict__ off, const int* __restrict__ csr,
                      const float* __restrict__ bias, const float* __restrict__ Wf,
                      float* __restrict__ hout, float* __restrict__ pool, int n) {
    int wv = threadIdx.x >> 6;
    int lane = threadIdx.x & 63;
    int node = blockIdx.x * 4 + wv;
    if (node >= n) return;
    int e0 = off[node], e1 = off[node + 1];
    float ax = 0.f, ay = 0.f;
    for (int base = e0; base < e1; base += 64) {
        int cnt = e1 - base; if (cnt > 64) cnt = 64;
        int idx = (base + lane < e1) ? csr[base + lane] : 0;
        for (int j = 0; j < cnt; ++j) {
            int s = __shfl(idx, j);
            float2 v = *(const float2*)&hs[(size_t)s * HID + lane * 2];
            ax += v.x; ay += v.y;
        }
    }
    float2 self = *(const float2*)&hs[(size_t)node * HID + lane * 2];
    float di = dinv[node];
    float hx = fmaxf(di * (ax + self.x) + bias[lane * 2 + 0], 0.f);
    float hy = fmaxf(di * (ay + self.y) + bias[lane * 2 + 1], 0.f);
    if (!POOL) {
        *(float2*)&hout[(size_t)node * HID + lane * 2] = make_float2(hx, hy);
    } else {
        float d = hx * Wf[lane * 2] + hy * Wf[lane * 2 + 1];
        #pragma unroll
        for (int o = 32; o > 0; o >>= 1) d += __shfl_down(d, o);
        if (lane == 0) atomicAdd(pool, d);
    }
}

__global__ void k_final(const float* __restrict__ pool, const float* __restrict__ bf,
                        float* __restrict__ out, float invn) {
    if (threadIdx.x == 0 && blockIdx.x == 0) out[0] = pool[0] * invn + bf[0];
}

extern "C" void kernel_launch(void* const* d_in, const int* in_sizes, int n_in,
                              void* d_out, int out_size, void* d_ws, size_t ws_size,
                              hipStream_t stream) {
    const float* x  = (const float*)d_in[0];
    const int*   ei = (const int*)d_in[1];
    const float* W1 = (const float*)d_in[2];
    const float* b1 = (const float*)d_in[3];
    const float* W2 = (const float*)d_in[4];
    const float* b2 = (const float*)d_in[5];
    const float* Wf = (const float*)d_in[6];
    const float* bf = (const float*)d_in[7];
    int n = in_sizes[0] / 3;
    int E = in_sizes[1] / 2;
    const int* src = ei;
    const int* dst = ei + E;

    char* w = (char*)d_ws;
    int*   deg    = (int*)(w + 0);                    // 400KB
    int*   off    = (int*)(w + (512ll << 10));        // 400KB (+1)
    int*   cursor = (int*)(w + (1024ll << 10));       // 400KB
    float* dinv   = (float*)(w + (1536ll << 10));     // 400KB
    float* pool   = (float*)(w + (2048ll << 10));     // 4B
    int*   csr    = (int*)(w + (2560ll << 10));       // 6.4MB
    float* hs     = (float*)(w + (10ll << 20));       // 51.2MB [10,62) — reused for hs2
    float* h1     = (float*)(w + (62ll << 20));       // 51.2MB [62,114)

    hipMemsetAsync(deg, 0, (size_t)n * sizeof(int), stream);
    hipMemsetAsync(pool, 0, sizeof(float), stream);

    k_deg<<<(E + 255) / 256, 256, 0, stream>>>(dst, deg, E);
    k_scan<<<1, 1024, 0, stream>>>(deg, off, cursor, n);
    k_dinv<<<(n + 255) / 256, 256, 0, stream>>>(deg, dinv, n);
    k_fill<<<(E + 255) / 256, 256, 0, stream>>>(src, dst, cursor, csr, E);

    k_gemm1<<<(n + 7) / 8, 256, 0, stream>>>(x, W1, dinv, hs, n);
    k_agg<false><<<(n + 3) / 4, 256, 0, stream>>>(hs, dinv, off, csr, b1, nullptr, h1, nullptr, n);
    k_gemm2<<<(n + 63) / 64, 256, 0, stream>>>(h1, W2, dinv, hs, n);
    k_agg<true><<<(n + 3) / 4, 256, 0, stream>>>(hs, dinv, off, csr, b2, Wf, nullptr, pool, n);
    k_final<<<1, 64, 0, stream>>>(pool, bf, (float*)d_out, 1.0f / (float)n);
}

// Round 6
// 1947.630 us; speedup vs baseline: 1.0050x; 1.0050x over previous
//
#include <hip/hip_runtime.h>
#include <hip/hip_bf16.h>
#include <cstdint>
#include <cstddef>

// GCN: h1 = relu(GCNConv(x;W1,b1)); h2 = relu(GCNConv(h1;W2,b2));
// out = mean(h2,axis=0) @ Wf + bf
// agg[i] = dinv[i] * ( sum_{e:dst=i} hs[src_e] + hs[i] ),  hs = (X@W)*dinv.
// k_agg v2: 32-lane float4 rows, 2 edges/wave-step, 4x unrolled => 8 loads in flight.

#define HID 128

__global__ void k_deg(const int* __restrict__ dst, int* __restrict__ deg, int E) {
    int e = blockIdx.x * 256 + threadIdx.x;
    if (e < E) atomicAdd(&deg[dst[e]], 1);
}

__global__ void k_scan(const int* __restrict__ deg, int* __restrict__ off,
                       int* __restrict__ cursor, int n) {
    __shared__ int sb[1024];
    int t = threadIdx.x;
    int chunk = (n + 1023) >> 10;
    int lo = t * chunk;
    int hi = lo + chunk; if (hi > n) hi = n;
    int s = 0;
    for (int i = lo; i < hi; ++i) s += deg[i];
    sb[t] = s;
    __syncthreads();
    for (int o = 1; o < 1024; o <<= 1) {
        int v = (t >= o) ? sb[t - o] : 0;
        __syncthreads();
        sb[t] += v;
        __syncthreads();
    }
    int run = sb[t] - s;
    for (int i = lo; i < hi; ++i) {
        off[i] = run; cursor[i] = run;
        run += deg[i];
    }
    if (t == 1023) off[n] = sb[1023];
}

__global__ void k_dinv(const int* __restrict__ deg, float* __restrict__ dinv, int n) {
    int i = blockIdx.x * 256 + threadIdx.x;
    if (i < n) dinv[i] = rsqrtf((float)(deg[i] + 1));
}

__global__ void k_fill(const int* __restrict__ src, const int* __restrict__ dst,
                       int* __restrict__ cursor, int* __restrict__ csr, int E) {
    int e = blockIdx.x * 256 + threadIdx.x;
    if (e < E) {
        int d = dst[e];
        int p = atomicAdd(&cursor[d], 1);
        csr[p] = src[e];
    }
}

__global__ void k_gemm1(const float* __restrict__ x, const float* __restrict__ W1,
                        const float* __restrict__ dinv, float* __restrict__ hs, int n) {
    int tc = threadIdx.x & 31;
    int tn = threadIdx.x >> 5;
    int i = blockIdx.x * 8 + tn;
    if (i >= n) return;
    float x0 = x[i * 3 + 0], x1 = x[i * 3 + 1], x2 = x[i * 3 + 2];
    float4 w0 = *(const float4*)&W1[0 * HID + tc * 4];
    float4 w1 = *(const float4*)&W1[1 * HID + tc * 4];
    float4 w2 = *(const float4*)&W1[2 * HID + tc * 4];
    float di = dinv[i];
    float4 r;
    r.x = (x0 * w0.x + x1 * w1.x + x2 * w2.x) * di;
    r.y = (x0 * w0.y + x1 * w1.y + x2 * w2.y) * di;
    r.z = (x0 * w0.z + x1 * w1.z + x2 * w2.z) * di;
    r.w = (x0 * w0.w + x1 * w1.w + x2 * w2.w) * di;
    *(float4*)&hs[(size_t)i * HID + tc * 4] = r;
}

__global__ __launch_bounds__(256) void k_gemm2(const float* __restrict__ h,
                                               const float* __restrict__ W,
                                               const float* __restrict__ dinv,
                                               float* __restrict__ hs, int n) {
    __shared__ float hl[64][16];
    __shared__ float wl[16][128];
    int tid = threadIdx.x;
    int r0 = blockIdx.x * 64;
    int tr = tid >> 5;
    int tc = tid & 31;
    float4 acc[8];
    #pragma unroll
    for (int r = 0; r < 8; ++r) acc[r] = make_float4(0.f, 0.f, 0.f, 0.f);

    for (int k0 = 0; k0 < HID; k0 += 16) {
        int lr = tid >> 2, lk = (tid & 3) * 4;
        float4 hv = make_float4(0.f, 0.f, 0.f, 0.f);
        if (r0 + lr < n) hv = *(const float4*)&h[(size_t)(r0 + lr) * HID + k0 + lk];
        *(float4*)&hl[lr][lk] = hv;
        #pragma unroll
        for (int q = 0; q < 2; ++q) {
            int idx = tid + q * 256;
            int kr = idx >> 5, c4 = (idx & 31) * 4;
            *(float4*)&wl[kr][c4] = *(const float4*)&W[(size_t)(k0 + kr) * HID + c4];
        }
        __syncthreads();
        #pragma unroll
        for (int kk = 0; kk < 16; ++kk) {
            float4 w = *(const float4*)&wl[kk][tc * 4];
            #pragma unroll
            for (int r = 0; r < 8; ++r) {
                float hv2 = hl[tr * 8 + r][kk];
                acc[r].x += hv2 * w.x; acc[r].y += hv2 * w.y;
                acc[r].z += hv2 * w.z; acc[r].w += hv2 * w.w;
            }
        }
        __syncthreads();
    }
    #pragma unroll
    for (int r = 0; r < 8; ++r) {
        int row = r0 + tr * 8 + r;
        if (row < n) {
            float di = dinv[row];
            float4 v = acc[r];
            v.x *= di; v.y *= di; v.z *= di; v.w *= di;
            *(float4*)&hs[(size_t)row * HID + tc * 4] = v;
        }
    }
}

// ---- aggregation v2: one wave per node; 32 lanes x float4 per row;
// two edges per step (half-wave each); 4x unroll => 8 loads in flight ----
template <bool POOL>
__global__ __launch_bounds__(256) void k_agg(const float* __restrict__ hs,
                                             const float* __restrict__ dinv,
                                             const int* __restrict__ off,
                                             const int* __restrict__ csr,
                                             const float* __restrict__ bias,
                                             const float* __restrict__ Wf,
                                             float* __restrict__ hout,
                                             float* __restrict__ pool, int n) {
    int wv = threadIdx.x >> 6;
    int lane = threadIdx.x & 63;
    int half = lane >> 5;     // which edge of a pair
    int col = lane & 31;      // float4 column within the 128-float row
    int node = blockIdx.x * 4 + wv;
    if (node >= n) return;
    int e0 = off[node], e1 = off[node + 1];
    float ax = 0.f, ay = 0.f, az = 0.f, aw = 0.f;

    for (int base = e0; base < e1; base += 64) {
        int m = e1 - base; if (m > 64) m = 64;
        int idx = (base + lane < e1) ? csr[base + lane] : 0;
        int j = 0;
        for (; j + 8 <= m; j += 8) {
            int s0 = __shfl(idx, j + 0 + half);
            int s1 = __shfl(idx, j + 2 + half);
            int s2 = __shfl(idx, j + 4 + half);
            int s3 = __shfl(idx, j + 6 + half);
            float4 v0 = *(const float4*)&hs[(size_t)s0 * HID + col * 4];
            float4 v1 = *(const float4*)&hs[(size_t)s1 * HID + col * 4];
            float4 v2 = *(const float4*)&hs[(size_t)s2 * HID + col * 4];
            float4 v3 = *(const float4*)&hs[(size_t)s3 * HID + col * 4];
            ax += v0.x + v1.x + v2.x + v3.x;
            ay += v0.y + v1.y + v2.y + v3.y;
            az += v0.z + v1.z + v2.z + v3.z;
            aw += v0.w + v1.w + v2.w + v3.w;
        }
        for (; j < m; j += 2) {
            int jj = j + half;
            if (jj < m) {
                int s = __shfl(idx, jj);
                float4 v = *(const float4*)&hs[(size_t)s * HID + col * 4];
                ax += v.x; ay += v.y; az += v.z; aw += v.w;
            }
        }
    }
    // fold the two half-wave partials into lanes 0-31
    ax += __shfl_down(ax, 32);
    ay += __shfl_down(ay, 32);
    az += __shfl_down(az, 32);
    aw += __shfl_down(aw, 32);

    if (half == 0) {
        float4 self = *(const float4*)&hs[(size_t)node * HID + col * 4];
        float di = dinv[node];
        float4 b = *(const float4*)&bias[col * 4];
        float hx = fmaxf(di * (ax + self.x) + b.x, 0.f);
        float hy = fmaxf(di * (ay + self.y) + b.y, 0.f);
        float hz = fmaxf(di * (az + self.z) + b.z, 0.f);
        float hw = fmaxf(di * (aw + self.w) + b.w, 0.f);
        if (!POOL) {
            *(float4*)&hout[(size_t)node * HID + col * 4] = make_float4(hx, hy, hz, hw);
        } else {
            float4 wf = *(const float4*)&Wf[col * 4];
            float d = hx * wf.x + hy * wf.y + hz * wf.z + hw * wf.w;
            #pragma unroll
            for (int o = 16; o > 0; o >>= 1) d += __shfl_down(d, o);
            if (col == 0) atomicAdd(pool, d);
        }
    }
}

__global__ void k_final(const float* __restrict__ pool, const float* __restrict__ bf,
                        float* __restrict__ out, float invn) {
    if (threadIdx.x == 0 && blockIdx.x == 0) out[0] = pool[0] * invn + bf[0];
}

extern "C" void kernel_launch(void* const* d_in, const int* in_sizes, int n_in,
                              void* d_out, int out_size, void* d_ws, size_t ws_size,
                              hipStream_t stream) {
    const float* x  = (const float*)d_in[0];
    const int*   ei = (const int*)d_in[1];
    const float* W1 = (const float*)d_in[2];
    const float* b1 = (const float*)d_in[3];
    const float* W2 = (const float*)d_in[4];
    const float* b2 = (const float*)d_in[5];
    const float* Wf = (const float*)d_in[6];
    const float* bf = (const float*)d_in[7];
    int n = in_sizes[0] / 3;
    int E = in_sizes[1] / 2;
    const int* src = ei;
    const int* dst = ei + E;

    char* w = (char*)d_ws;
    int*   deg    = (int*)(w + 0);                    // 400KB
    int*   off    = (int*)(w + (512ll << 10));        // 400KB (+1)
    int*   cursor = (int*)(w + (1024ll << 10));       // 400KB
    float* dinv   = (float*)(w + (1536ll << 10));     // 400KB
    float* pool   = (float*)(w + (2048ll << 10));     // 4B
    int*   csr    = (int*)(w + (2560ll << 10));       // 6.4MB
    float* hs     = (float*)(w + (10ll << 20));       // 51.2MB — reused for hs2
    float* h1     = (float*)(w + (62ll << 20));       // 51.2MB

    hipMemsetAsync(deg, 0, (size_t)n * sizeof(int), stream);
    hipMemsetAsync(pool, 0, sizeof(float), stream);

    k_deg<<<(E + 255) / 256, 256, 0, stream>>>(dst, deg, E);
    k_scan<<<1, 1024, 0, stream>>>(deg, off, cursor, n);
    k_dinv<<<(n + 255) / 256, 256, 0, stream>>>(deg, dinv, n);
    k_fill<<<(E + 255) / 256, 256, 0, stream>>>(src, dst, cursor, csr, E);

    k_gemm1<<<(n + 7) / 8, 256, 0, stream>>>(x, W1, dinv, hs, n);
    k_agg<false><<<(n + 3) / 4, 256, 0, stream>>>(hs, dinv, off, csr, b1, nullptr, h1, nullptr, n);
    k_gemm2<<<(n + 63) / 64, 256, 0, stream>>>(h1, W2, dinv, hs, n);
    k_agg<true><<<(n + 3) / 4, 256, 0, stream>>>(hs, dinv, off, csr, b2, Wf, nullptr, pool, n);
    k_final<<<1, 64, 0, stream>>>(pool, bf, (float*)d_out, 1.0f / (float)n);
}

// Round 7
// 685.142 us; speedup vs baseline: 2.8568x; 2.8427x over previous
//
#include <hip/hip_runtime.h>
#include <hip/hip_bf16.h>
#include <cstdint>
#include <cstddef>

// GCN restructured:
//   conv1: agg RAW 3-dim features (16B/edge from L2-resident 1.6MB table), W1 AFTER agg.
//   conv2: agg h1s rows stored bf16 (256B/edge), W2 AFTER agg, relu+Wf+pool fused in GEMM.
// agg[i] = dinv[i]*(sum_{e:dst=i} v[src] + v[i]),  v = feat*dinv.

#define HID 128

__device__ inline float bflo(unsigned u) { return __uint_as_float(u << 16); }
__device__ inline float bfhi(unsigned u) { return __uint_as_float(u & 0xffff0000u); }

__global__ void k_deg(const int* __restrict__ dst, int* __restrict__ deg, int E) {
    int e = blockIdx.x * 256 + threadIdx.x;
    if (e < E) atomicAdd(&deg[dst[e]], 1);
}

__global__ void k_scan(const int* __restrict__ deg, int* __restrict__ off,
                       int* __restrict__ cursor, int n) {
    __shared__ int sb[1024];
    int t = threadIdx.x;
    int chunk = (n + 1023) >> 10;
    int lo = t * chunk;
    int hi = lo + chunk; if (hi > n) hi = n;
    int s = 0;
    for (int i = lo; i < hi; ++i) s += deg[i];
    sb[t] = s;
    __syncthreads();
    for (int o = 1; o < 1024; o <<= 1) {
        int v = (t >= o) ? sb[t - o] : 0;
        __syncthreads();
        sb[t] += v;
        __syncthreads();
    }
    int run = sb[t] - s;
    for (int i = lo; i < hi; ++i) {
        off[i] = run; cursor[i] = run;
        run += deg[i];
    }
    if (t == 1023) off[n] = sb[1023];
}

__global__ void k_dinv(const int* __restrict__ deg, float* __restrict__ dinv, int n) {
    int i = blockIdx.x * 256 + threadIdx.x;
    if (i < n) dinv[i] = rsqrtf((float)(deg[i] + 1));
}

__global__ void k_fill(const int* __restrict__ src, const int* __restrict__ dst,
                       int* __restrict__ cursor, int* __restrict__ csr, int E) {
    int e = blockIdx.x * 256 + threadIdx.x;
    if (e < E) {
        int d = dst[e];
        int p = atomicAdd(&cursor[d], 1);
        csr[p] = src[e];
    }
}

// xs[i] = {x[i]*dinv[i] (3), dinv[i]}  — 16B/node, 1.6MB table (L2-resident)
__global__ void k_xs(const float* __restrict__ x, const float* __restrict__ dinv,
                     float4* __restrict__ xs, int n) {
    int i = blockIdx.x * 256 + threadIdx.x;
    if (i >= n) return;
    float di = dinv[i];
    xs[i] = make_float4(x[i * 3 + 0] * di, x[i * 3 + 1] * di, x[i * 3 + 2] * di, di);
}

// conv1 aggregation on 3-dim raw features: one THREAD per node, 4x unrolled.
__global__ void k_agg1(const float4* __restrict__ xs, const int* __restrict__ off,
                       const int* __restrict__ csr, float4* __restrict__ agg1, int n) {
    int i = blockIdx.x * 256 + threadIdx.x;
    if (i >= n) return;
    int e0 = off[i], e1 = off[i + 1];
    float sx = 0.f, sy = 0.f, sz = 0.f;
    int e = e0;
    for (; e + 4 <= e1; e += 4) {
        int s0 = csr[e], s1 = csr[e + 1], s2 = csr[e + 2], s3 = csr[e + 3];
        float4 v0 = xs[s0], v1 = xs[s1], v2 = xs[s2], v3 = xs[s3];
        sx += v0.x + v1.x + v2.x + v3.x;
        sy += v0.y + v1.y + v2.y + v3.y;
        sz += v0.z + v1.z + v2.z + v3.z;
    }
    for (; e < e1; ++e) {
        float4 v = xs[csr[e]];
        sx += v.x; sy += v.y; sz += v.z;
    }
    float4 self = xs[i];
    float di = self.w;
    agg1[i] = make_float4((sx + self.x) * di, (sy + self.y) * di, (sz + self.z) * di, di);
}

// h1s[i] = bf16( relu(agg1[i].xyz @ W1 + b1) * dinv )  — wave per node, 2 cols/lane
__global__ __launch_bounds__(256) void k_h1(const float4* __restrict__ agg1,
                                            const float* __restrict__ W1,
                                            const float* __restrict__ b1,
                                            unsigned short* __restrict__ h1s, int n) {
    int wv = threadIdx.x >> 6;
    int lane = threadIdx.x & 63;
    int i = blockIdx.x * 4 + wv;
    if (i >= n) return;
    int c0 = lane * 2;
    float4 a = agg1[i];
    float h0 = fmaxf(a.x * W1[0 * HID + c0]     + a.y * W1[1 * HID + c0]     + a.z * W1[2 * HID + c0]     + b1[c0],     0.f) * a.w;
    float h1 = fmaxf(a.x * W1[0 * HID + c0 + 1] + a.y * W1[1 * HID + c0 + 1] + a.z * W1[2 * HID + c0 + 1] + b1[c0 + 1], 0.f) * a.w;
    __hip_bfloat16 q0 = __float2bfloat16(h0);
    __hip_bfloat16 q1 = __float2bfloat16(h1);
    ushort2 pk;
    pk.x = *(unsigned short*)&q0;
    pk.y = *(unsigned short*)&q1;
    *(ushort2*)&h1s[(size_t)i * HID + c0] = pk;
}

// conv2 aggregation over bf16 rows (256B each): wave per node, 32 lanes x 8B,
// 2 edges per step (half-waves), 4x unroll.
__global__ __launch_bounds__(256) void k_agg2(const unsigned short* __restrict__ h1s,
                                              const float* __restrict__ dinv,
                                              const int* __restrict__ off,
                                              const int* __restrict__ csr,
                                              float* __restrict__ g2, int n) {
    int wv = threadIdx.x >> 6;
    int lane = threadIdx.x & 63;
    int half = lane >> 5;
    int col = lane & 31;          // owns cols 4c..4c+3
    int node = blockIdx.x * 4 + wv;
    if (node >= n) return;
    int e0 = off[node], e1 = off[node + 1];
    float ax = 0.f, ay = 0.f, az = 0.f, aw = 0.f;

    for (int base = e0; base < e1; base += 64) {
        int m = e1 - base; if (m > 64) m = 64;
        int idx = (base + lane < e1) ? csr[base + lane] : 0;
        int j = 0;
        for (; j + 8 <= m; j += 8) {
            int s0 = __shfl(idx, j + 0 + half);
            int s1 = __shfl(idx, j + 2 + half);
            int s2 = __shfl(idx, j + 4 + half);
            int s3 = __shfl(idx, j + 6 + half);
            uint2 r0 = *(const uint2*)&h1s[(size_t)s0 * HID + col * 4];
            uint2 r1 = *(const uint2*)&h1s[(size_t)s1 * HID + col * 4];
            uint2 r2 = *(const uint2*)&h1s[(size_t)s2 * HID + col * 4];
            uint2 r3 = *(const uint2*)&h1s[(size_t)s3 * HID + col * 4];
            ax += bflo(r0.x) + bflo(r1.x) + bflo(r2.x) + bflo(r3.x);
            ay += bfhi(r0.x) + bfhi(r1.x) + bfhi(r2.x) + bfhi(r3.x);
            az += bflo(r0.y) + bflo(r1.y) + bflo(r2.y) + bflo(r3.y);
            aw += bfhi(r0.y) + bfhi(r1.y) + bfhi(r2.y) + bfhi(r3.y);
        }
        for (; j < m; j += 2) {
            int jj = j + half;
            if (jj < m) {
                int s = __shfl(idx, jj);
                uint2 r = *(const uint2*)&h1s[(size_t)s * HID + col * 4];
                ax += bflo(r.x); ay += bfhi(r.x);
                az += bflo(r.y); aw += bfhi(r.y);
            }
        }
    }
    ax += __shfl_down(ax, 32);
    ay += __shfl_down(ay, 32);
    az += __shfl_down(az, 32);
    aw += __shfl_down(aw, 32);

    if (half == 0) {
        uint2 r = *(const uint2*)&h1s[(size_t)node * HID + col * 4];
        float di = dinv[node];
        float4 o;
        o.x = (ax + bflo(r.x)) * di;
        o.y = (ay + bfhi(r.x)) * di;
        o.z = (az + bflo(r.y)) * di;
        o.w = (aw + bfhi(r.y)) * di;
        *(float4*)&g2[(size_t)node * HID + col * 4] = o;
    }
}

// h2 = relu(g2 @ W2 + b2); fused epilogue: pool += sum_rows h2 . Wf
__global__ __launch_bounds__(256) void k_gemm2b(const float* __restrict__ g2,
                                                const float* __restrict__ W,
                                                const float* __restrict__ b2,
                                                const float* __restrict__ Wf,
                                                float* __restrict__ pool, int n) {
    __shared__ float hl[64][16];
    __shared__ float wl[16][128];
    int tid = threadIdx.x;
    int r0 = blockIdx.x * 64;
    int tr = tid >> 5;
    int tc = tid & 31;
    float4 acc[8];
    #pragma unroll
    for (int r = 0; r < 8; ++r) acc[r] = make_float4(0.f, 0.f, 0.f, 0.f);

    for (int k0 = 0; k0 < HID; k0 += 16) {
        int lr = tid >> 2, lk = (tid & 3) * 4;
        float4 hv = make_float4(0.f, 0.f, 0.f, 0.f);
        if (r0 + lr < n) hv = *(const float4*)&g2[(size_t)(r0 + lr) * HID + k0 + lk];
        *(float4*)&hl[lr][lk] = hv;
        #pragma unroll
        for (int q = 0; q < 2; ++q) {
            int idx = tid + q * 256;
            int kr = idx >> 5, c4 = (idx & 31) * 4;
            *(float4*)&wl[kr][c4] = *(const float4*)&W[(size_t)(k0 + kr) * HID + c4];
        }
        __syncthreads();
        #pragma unroll
        for (int kk = 0; kk < 16; ++kk) {
            float4 w = *(const float4*)&wl[kk][tc * 4];
            #pragma unroll
            for (int r = 0; r < 8; ++r) {
                float hv2 = hl[tr * 8 + r][kk];
                acc[r].x += hv2 * w.x; acc[r].y += hv2 * w.y;
                acc[r].z += hv2 * w.z; acc[r].w += hv2 * w.w;
            }
        }
        __syncthreads();
    }
    float4 bb = *(const float4*)&b2[tc * 4];
    float4 wf = *(const float4*)&Wf[tc * 4];
    float d = 0.f;
    #pragma unroll
    for (int r = 0; r < 8; ++r) {
        int row = r0 + tr * 8 + r;
        if (row < n) {
            float hx = fmaxf(acc[r].x + bb.x, 0.f);
            float hy = fmaxf(acc[r].y + bb.y, 0.f);
            float hz = fmaxf(acc[r].z + bb.z, 0.f);
            float hw = fmaxf(acc[r].w + bb.w, 0.f);
            d += hx * wf.x + hy * wf.y + hz * wf.z + hw * wf.w;
        }
    }
    #pragma unroll
    for (int o = 16; o > 0; o >>= 1) d += __shfl_down(d, o, 32);
    if ((tid & 31) == 0) atomicAdd(pool, d);
}

__global__ void k_final(const float* __restrict__ pool, const float* __restrict__ bf,
                        float* __restrict__ out, float invn) {
    if (threadIdx.x == 0 && blockIdx.x == 0) out[0] = pool[0] * invn + bf[0];
}

extern "C" void kernel_launch(void* const* d_in, const int* in_sizes, int n_in,
                              void* d_out, int out_size, void* d_ws, size_t ws_size,
                              hipStream_t stream) {
    const float* x  = (const float*)d_in[0];
    const int*   ei = (const int*)d_in[1];
    const float* W1 = (const float*)d_in[2];
    const float* b1 = (const float*)d_in[3];
    const float* W2 = (const float*)d_in[4];
    const float* b2 = (const float*)d_in[5];
    const float* Wf = (const float*)d_in[6];
    const float* bf = (const float*)d_in[7];
    int n = in_sizes[0] / 3;
    int E = in_sizes[1] / 2;
    const int* src = ei;
    const int* dst = ei + E;

    char* w = (char*)d_ws;
    int*    deg    = (int*)(w + 0);                    // 400KB
    int*    off    = (int*)(w + (512ll << 10));        // 400KB (+1)
    int*    cursor = (int*)(w + (1024ll << 10));       // 400KB
    float*  dinv   = (float*)(w + (1536ll << 10));     // 400KB
    float*  pool   = (float*)(w + (2048ll << 10));     // 4B
    int*    csr    = (int*)(w + (2560ll << 10));       // 6.4MB  [2.5,8.9)MB
    float4* xs     = (float4*)(w + (9ll << 20));       // 1.6MB  [9,10.6)
    float4* agg1   = (float4*)(w + (11ll << 20));      // 1.6MB  [11,12.6)
    unsigned short* h1s = (unsigned short*)(w + (13ll << 20)); // 25.6MB [13,38.6)
    float*  g2     = (float*)(w + (39ll << 20));       // 51.2MB [39,90.2)

    hipMemsetAsync(deg, 0, (size_t)n * sizeof(int), stream);
    hipMemsetAsync(pool, 0, sizeof(float), stream);

    k_deg<<<(E + 255) / 256, 256, 0, stream>>>(dst, deg, E);
    k_scan<<<1, 1024, 0, stream>>>(deg, off, cursor, n);
    k_dinv<<<(n + 255) / 256, 256, 0, stream>>>(deg, dinv, n);
    k_fill<<<(E + 255) / 256, 256, 0, stream>>>(src, dst, cursor, csr, E);

    k_xs<<<(n + 255) / 256, 256, 0, stream>>>(x, dinv, xs, n);
    k_agg1<<<(n + 255) / 256, 256, 0, stream>>>(xs, off, csr, agg1, n);
    k_h1<<<(n + 3) / 4, 256, 0, stream>>>(agg1, W1, b1, h1s, n);
    k_agg2<<<(n + 3) / 4, 256, 0, stream>>>(h1s, dinv, off, csr, g2, n);
    k_gemm2b<<<(n + 63) / 64, 256, 0, stream>>>(g2, W2, b2, Wf, pool, n);
    k_final<<<1, 64, 0, stream>>>(pool, bf, (float*)d_out, 1.0f / (float)n);
}